// Round 7
// baseline (209.080 us; speedup 1.0000x reference)
//
#include <hip/hip_runtime.h>
#include <hip/hip_bf16.h>

#define Hh 512
#define Pp 256
#define Ll 4096
#define Bb 8
#define BL (Bb*Ll)      // 32768
#define Sc 64
#define NC 64

typedef __attribute__((ext_vector_type(8))) __bf16 bf16x8;
typedef __attribute__((ext_vector_type(4))) float  floatx4;

// ws offsets in float2 units (8 B each; all 16B-aligned)
#define LAM_OFF     0                        // f32 lambda_bar [256]
#define LAMS64D_OFF 512                      // double2 lambda^64 [256] (512 slots)
#define B1G_OFF     1024                     // bf16 [512 n][512 k]
#define B3G_OFF     (B1G_OFF + 65536)        // bf16 [512 n][512 k]
#define UB16_OFF    (B3G_OFF + 65536)        // bf16 u [32768][512]
#define BUB_OFF     (UB16_OFF + 4194304)     // bf16 Bu [32768][512]
#define XSB_OFF     (BUB_OFF + 4194304)      // reused: lam16 + agg16
#define AGG_OFF     (XSB_OFF + 4194304)      // float2 [512*256]

#define LAMS16D_OFF XSB_OFF                  // double2 lambda^16 [256] (512 slots)
#define AGG16_OFF   (XSB_OFF + 512)          // float2 [2048][256] sub-chunk aggs

#define OUT_ELEMS 16777216                   // then state planar [2048 re][2048 im]

#define GLL16(g, l) __builtin_amdgcn_global_load_lds( \
    (const __attribute__((address_space(1))) void*)(g), \
    (__attribute__((address_space(3))) void*)(l), 16, 0, 0)

#define BAR_LGKM()  asm volatile("s_waitcnt lgkmcnt(0)\n\ts_barrier" ::: "memory")
#define BAR_VMN(n)  asm volatile("s_waitcnt vmcnt(" #n ")\n\ts_barrier" ::: "memory")

__device__ __forceinline__ float2 cmul(float2 a, float2 b) {
    return make_float2(a.x*b.x - a.y*b.y, a.x*b.y + a.y*b.x);
}
__device__ __forceinline__ void cfma(float2& acc, float2 a, float2 b) {
    acc.x = fmaf(a.x, b.x, acc.x); acc.x = fmaf(-a.y, b.y, acc.x);
    acc.y = fmaf(a.x, b.y, acc.y); acc.y = fmaf( a.y, b.x, acc.y);
}

// ---- PREP: grid 9217 (unchanged) ----
__global__ void prep(const float* __restrict__ u,
                     const float* __restrict__ Bmat, const float* __restrict__ Cmat,
                     const float* __restrict__ Lre, const float* __restrict__ Lim,
                     const float* __restrict__ logstep, float2* __restrict__ ws) {
    int bid = blockIdx.x;
    if (bid < 8192) {
        long i = ((long)bid * 256 + threadIdx.x) * 8;
        float4 v0 = *(const float4*)(u + i);
        float4 v1 = *(const float4*)(u + i + 4);
        __align__(16) __hip_bfloat162 t[4];
        t[0] = __float22bfloat162_rn(make_float2(v0.x, v0.y));
        t[1] = __float22bfloat162_rn(make_float2(v0.z, v0.w));
        t[2] = __float22bfloat162_rn(make_float2(v1.x, v1.y));
        t[3] = __float22bfloat162_rn(make_float2(v1.z, v1.w));
        *(bf16x8*)((__hip_bfloat16*)(ws + UB16_OFF) + i) = *(const bf16x8*)t;
    } else if (bid < 8704) {
        int idx = (bid - 8192) * 256 + threadIdx.x;  // = p*512+h
        int p = idx >> 9, h = idx & 511;
        double lr = (double)Lre[p], li = (double)Lim[p];
        double st = exp((double)logstep[p]);
        double a  = lr * st, th = li * st;
        double er = exp(a);
        double lamr = er * cos(th), lami = er * sin(th);
        double nr = lamr - 1.0, ni = lami;
        double den = lr*lr + li*li;
        float gx = (float)((nr*lr + ni*li)/den), gy = (float)((ni*lr - nr*li)/den);
        float2 b = ((const float2*)Bmat)[idx];
        float re = gx*b.x - gy*b.y;
        float im = gx*b.y + gy*b.x;
        __hip_bfloat16* B1 = (__hip_bfloat16*)(ws + B1G_OFF);
        B1[(2*p)*512 + h]   = __float2bfloat16(re);
        B1[(2*p+1)*512 + h] = __float2bfloat16(im);
    } else if (bid < 9216) {
        int idx = (bid - 8704) * 256 + threadIdx.x;  // = h*256+p
        int h = idx >> 8, p = idx & 255;
        float2 c = ((const float2*)Cmat)[idx];
        __hip_bfloat162* B3 = (__hip_bfloat162*)(ws + B3G_OFF);
        B3[h*256 + p] = __float22bfloat162_rn(make_float2(2.f*c.x, -2.f*c.y));
    } else {
        int p = threadIdx.x;
        double lr = (double)Lre[p], li = (double)Lim[p];
        double st = exp((double)logstep[p]);
        double a  = lr * st, th = li * st;
        double er = exp(a);
        ws[LAM_OFF + p] = make_float2((float)(er*cos(th)), (float)(er*sin(th)));
        double er64 = exp(64.0 * a), th64 = 64.0 * th;
        ((double2*)(ws + LAMS64D_OFF))[p] = make_double2(er64*cos(th64), er64*sin(th64));
        double er16 = exp(16.0 * a), th16 = 16.0 * th;
        ((double2*)(ws + LAMS16D_OFF))[p] = make_double2(er16*cos(th16), er16*sin(th16));
    }
}

// ---- GEMM1: 16-wave 256x256, BK=64, counted-vmcnt pipeline, fused k2a epi ----
// 1024 threads = 16 waves (4M x 4N), each wave 64x64 output (acc 4x4 frags).
// Staging per tile: 2 A + 2 B gll16 per thread (h_ covers 128-row halves).
#define STAGE(buf, kt) do { \
    _Pragma("unroll") \
    for (int h_ = 0; h_ < 2; ++h_) { \
        GLL16(aSrc + (h_*128)*1024 + (kt)*128, \
              ldsSt + (buf)*65536 + h_*16384); \
        GLL16(bSrc + (h_*128)*1024 + (kt)*128, \
              ldsSt + (buf)*65536 + 32768 + h_*16384); \
    } \
} while (0)

__global__ __launch_bounds__(1024)
void gemm1(const __hip_bfloat16* __restrict__ A,
           const __hip_bfloat16* __restrict__ B,
           void* __restrict__ Cout,
           const float2* __restrict__ lamTab,
           float2* __restrict__ aggOut,
           float2* __restrict__ agg16Out) {
    __shared__ __align__(16) char lds[131072];
    const int tid = threadIdx.x;
    const int w = tid >> 6, l = tid & 63;

    const int idx = blockIdx.x;
    const int swz = (idx & 7) * 32 + (idx >> 3);     // T1 bijective XCD swizzle
    const int mt = swz >> 1, nt = swz & 1;
    const long M0 = (long)mt * 256;
    const int  N0 = nt * 256;

    const int rA  = l >> 3;
    const int csw = ((l & 7) ^ rA) * 16;             // T2 inverse-source swizzle
    const char* aSrc = (const char*)A + (M0 + w*8 + rA) * 1024 + csw;
    const char* bSrc = (const char*)B + (long)(N0 + w*8 + rA) * 1024 + csw;
    char* ldsSt = lds + w*1024 + l*16;

    const int quad = l >> 4, ml = l & 15, m7 = ml & 7;
    const int wm = w & 3, wn = w >> 2;
    const int o0 = ((quad    ) ^ m7) * 16;
    const int o1 = ((quad + 4) ^ m7) * 16;
    const char* aRd = lds + wm*8192 + ml*128;
    const char* bRd = lds + 32768 + wn*8192 + ml*128;

    floatx4 acc[4][4];
    #pragma unroll
    for (int i = 0; i < 4; ++i)
        #pragma unroll
        for (int j = 0; j < 4; ++j) acc[i][j] = (floatx4)0.f;

    STAGE(0, 0);
    STAGE(1, 1);
    BAR_VMN(4);

    #pragma unroll
    for (int t = 0; t < 8; ++t) {
        const int tb = (t & 1) * 65536;
        {
            bf16x8 af[4], bfr[4];
            #pragma unroll
            for (int fm = 0; fm < 4; ++fm)
                af[fm] = *(const bf16x8*)(aRd + tb + fm*2048 + o0);
            #pragma unroll
            for (int fn = 0; fn < 4; ++fn)
                bfr[fn] = *(const bf16x8*)(bRd + tb + fn*2048 + o0);
            __builtin_amdgcn_s_setprio(1);
            #pragma unroll
            for (int fm = 0; fm < 4; ++fm)
                #pragma unroll
                for (int fn = 0; fn < 4; ++fn)
                    acc[fm][fn] = __builtin_amdgcn_mfma_f32_16x16x32_bf16(
                        af[fm], bfr[fn], acc[fm][fn], 0, 0, 0);
            __builtin_amdgcn_s_setprio(0);
        }
        {
            bf16x8 af[4], bfr[4];
            #pragma unroll
            for (int fm = 0; fm < 4; ++fm)
                af[fm] = *(const bf16x8*)(aRd + tb + fm*2048 + o1);
            #pragma unroll
            for (int fn = 0; fn < 4; ++fn)
                bfr[fn] = *(const bf16x8*)(bRd + tb + fn*2048 + o1);
            BAR_LGKM();
            if (t + 2 < 8) STAGE(t & 1, t + 2);
            __builtin_amdgcn_sched_barrier(0);
            __builtin_amdgcn_s_setprio(1);
            #pragma unroll
            for (int fm = 0; fm < 4; ++fm)
                #pragma unroll
                for (int fn = 0; fn < 4; ++fn)
                    acc[fm][fn] = __builtin_amdgcn_mfma_f32_16x16x32_bf16(
                        af[fm], bfr[fn], acc[fm][fn], 0, 0, 0);
            __builtin_amdgcn_s_setprio(0);
        }
        if (t < 6)       BAR_VMN(4);
        else if (t == 6) BAR_VMN(0);
    }

    // fused store + chunk-aggregate + sub-chunk A16. Wave wm owns chunk gc0+wm;
    // j = 16*fm + 4*quad + reg, weight lam^{63-j} = p16(fm)*P4q(quad)*lam^{3-reg}.
    const int b   = (int)(M0 >> 12);
    const int gc0 = (int)((M0 >> 6) & 63);
    const int gch = gc0 + wm;
    #pragma unroll
    for (int fn = 0; fn < 4; ++fn) {
        const int col = N0 + wn*64 + fn*16 + ml;
        const int p = col >> 1;
        const float2 lam = lamTab[p];
        const float2 one = make_float2(1.f, 0.f);
        const float2 l2  = cmul(lam, lam);
        const float2 l3  = cmul(l2, lam);
        const float2 l4  = cmul(l2, l2);
        const float2 l8  = cmul(l4, l4);
        const float2 l12 = cmul(l8, l4);
        const float2 l16 = cmul(l8, l8);
        const float2 l32 = cmul(l16, l16);
        const float2 l48 = cmul(l32, l16);
        const float2 P4q = (quad==3) ? one : (quad==2) ? l4 : (quad==1) ? l8 : l12;
        float2 sc = make_float2(0.f, 0.f);
        #pragma unroll
        for (int fm = 0; fm < 4; ++fm) {
            float vr[4];
            #pragma unroll
            for (int reg = 0; reg < 4; ++reg) {
                const long row = M0 + wm*64 + fm*16 + quad*4 + reg;
                __hip_bfloat16 hv = __float2bfloat16(acc[fm][fn][reg]);
                ((__hip_bfloat16*)Cout)[row * 512 + col] = hv;
                vr[reg] = __bfloat162float(hv);
            }
            float2 s;
            s.x = fmaf(l3.x, vr[0], fmaf(l2.x, vr[1], fmaf(lam.x, vr[2], vr[3])));
            s.y = fmaf(l3.y, vr[0], fmaf(l2.y, vr[1], lam.y * vr[2]));
            const float2 p16 = (fm==3) ? one : (fm==2) ? l16 : (fm==1) ? l32 : l48;
            cfma(sc, cmul(p16, P4q), s);
            float2 tq = cmul(P4q, s);
            tq.x += __shfl_xor(tq.x, 16); tq.y += __shfl_xor(tq.y, 16);
            tq.x += __shfl_xor(tq.x, 32); tq.y += __shfl_xor(tq.y, 32);
            const float tox = __shfl_xor(tq.x, 1);
            const float toy = __shfl_xor(tq.y, 1);
            if (quad == 0 && (ml & 1) == 0)
                agg16Out[((size_t)((b*NC + gch)*4 + fm))*Pp + p] =
                    make_float2(tq.x - toy, tq.y + tox);
        }
        sc.x += __shfl_xor(sc.x, 16); sc.y += __shfl_xor(sc.y, 16);
        sc.x += __shfl_xor(sc.x, 32); sc.y += __shfl_xor(sc.y, 32);
        const float ox = __shfl_xor(sc.x, 1);
        const float oy = __shfl_xor(sc.y, 1);
        if (quad == 0 && (ml & 1) == 0) {
            aggOut[(b*NC + gch) * Pp + p] = make_float2(sc.x - oy, sc.y + ox);
        }
    }
}

// ---- GEMM2F: 16-wave, LDS-staged Bu, in-place 512-thread scan ----
// LDS: A dbuf [0,64K) | B dbuf [64K,128K) | carry16 [128K,160K).
#define STAGEA2(buf, kt) do { \
    _Pragma("unroll") \
    for (int h_ = 0; h_ < 2; ++h_) { \
        GLL16(aSrc + (h_*128)*1024 + (kt)*128, \
              ldsA + (buf)*32768 + h_*16384); \
    } \
} while (0)
#define STAGEB2(buf, kt) do { \
    _Pragma("unroll") \
    for (int h_ = 0; h_ < 2; ++h_) { \
        GLL16(bSrc + (h_*128)*1024 + (kt)*128, \
              ldsB + (buf)*32768 + h_*16384); \
    } \
} while (0)

// in-place scan of one K-tile (32 complex p, 256 rows) by threads 0..511
#define SCAN_TILE(ktC, bufA) do { \
    if (tid < 512) { \
        const int s16_ = tid >> 5; \
        const float2 lam_ = lamK[ktC]; \
        float2 x_ = carry16L[s16_*256 + (ktC)*32 + p5g]; \
        char* base_ = lds + (bufA)*32768; \
        _Pragma("unroll") \
        for (int jj_ = 0; jj_ < 16; ++jj_) { \
            const int j_ = (s16_ << 4) + jj_; \
            char* cell_ = base_ + j_*128 + ((((p5g >> 2) ^ (j_ & 7)) << 4) | ((p5g & 3) << 2)); \
            float2 v_ = __bfloat1622float2(*(const __hip_bfloat162*)cell_); \
            float nr_ = fmaf(lam_.x, x_.x, v_.x); nr_ = fmaf(-lam_.y, x_.y, nr_); \
            float ni_ = fmaf(lam_.x, x_.y, v_.y); ni_ = fmaf( lam_.y, x_.x, ni_); \
            x_.x = nr_; x_.y = ni_; \
            *(__hip_bfloat162*)cell_ = __float22bfloat162_rn(x_); \
        } \
        if (s16_ == 15 && gc0 == 60 && nt == 0) { \
            out[OUT_ELEMS + b * Pp + (ktC)*32 + p5g] = x_.x; \
            out[OUT_ELEMS + Bb * Pp + b * Pp + (ktC)*32 + p5g] = x_.y; \
        } \
    } \
} while (0)

__global__ __launch_bounds__(1024)
void gemm2f(const __hip_bfloat16* __restrict__ A,   // Bu bf16 [32768][512]
            const __hip_bfloat16* __restrict__ Bg,  // B3G [512 n][512 k]
            float* __restrict__ out,
            const __hip_bfloat16* __restrict__ ub,
            const float* __restrict__ Dv,
            const float2* __restrict__ lamTab,
            const double2* __restrict__ lam64,
            const double2* __restrict__ lam16,
            const float2* __restrict__ agg,
            const float2* __restrict__ agg16) {
    __shared__ __align__(16) char lds[163840];
    const int tid = threadIdx.x;
    const int w = tid >> 6, l = tid & 63;
    const int idx = blockIdx.x;
    const int swz = (idx & 7) * 32 + (idx >> 3);
    const int mt = swz >> 1, nt = swz & 1;
    const long M0 = (long)mt * 256;
    const int  N0 = nt * 256;
    const int b   = (int)(M0 >> 12);
    const int gc0 = (int)((M0 >> 6) & 63);   // multiple of 4

    const int rA  = l >> 3;
    const int csw = ((l & 7) ^ rA) * 16;
    const char* aSrc = (const char*)A + (M0 + w*8 + rA) * 1024 + csw;
    const char* bSrc = (const char*)Bg + (long)(N0 + w*8 + rA) * 1024 + csw;
    char* ldsA = lds + w*1024 + l*16;
    char* ldsB = lds + 65536 + w*1024 + l*16;

    const int quad = l >> 4, ml = l & 15, m7 = ml & 7;
    const int wm = w & 3, wn = w >> 2;
    const int o0 = ((quad    ) ^ m7) * 16;
    const int o1 = ((quad + 4) ^ m7) * 16;
    const char* aRd = lds + wm*8192 + ml*128;
    const char* bRd = lds + 65536 + wn*8192 + ml*128;
    float2* carry16L = (float2*)(lds + 131072);   // [16][256]

    const int p5g = tid & 31;
    float2 lamK[8];
    #pragma unroll
    for (int kt = 0; kt < 8; ++kt) lamK[kt] = lamTab[kt*32 + p5g];

    STAGEA2(0, 0); STAGEB2(0, 0);
    STAGEA2(1, 1); STAGEB2(1, 1);

    // chunk carries (exact fp64 chain) + fp64 sub-chunk carries -> LDS
    if (tid < 256) {
        const int p = tid;
        const double2 l64 = lam64[p];
        const double2 l16 = lam16[p];
        double cr = 0.0, ci = 0.0;
        for (int cp = 0; cp + 4 <= gc0; cp += 4) {
            float2 a0 = agg[(b*NC + cp    ) * Pp + p];
            float2 a1 = agg[(b*NC + cp + 1) * Pp + p];
            float2 a2 = agg[(b*NC + cp + 2) * Pp + p];
            float2 a3 = agg[(b*NC + cp + 3) * Pp + p];
            double nr, ni;
            nr = fma(l64.x, cr, (double)a0.x); nr = fma(-l64.y, ci, nr);
            ni = fma(l64.x, ci, (double)a0.y); ni = fma( l64.y, cr, ni); cr = nr; ci = ni;
            nr = fma(l64.x, cr, (double)a1.x); nr = fma(-l64.y, ci, nr);
            ni = fma(l64.x, ci, (double)a1.y); ni = fma( l64.y, cr, ni); cr = nr; ci = ni;
            nr = fma(l64.x, cr, (double)a2.x); nr = fma(-l64.y, ci, nr);
            ni = fma(l64.x, ci, (double)a2.y); ni = fma( l64.y, cr, ni); cr = nr; ci = ni;
            nr = fma(l64.x, cr, (double)a3.x); nr = fma(-l64.y, ci, nr);
            ni = fma(l64.x, ci, (double)a3.y); ni = fma( l64.y, cr, ni); cr = nr; ci = ni;
        }
        #pragma unroll
        for (int ch = 0; ch < 4; ++ch) {
            carry16L[(ch*4 + 0)*256 + p] = make_float2((float)cr, (float)ci);
            double scr = cr, sci = ci;
            #pragma unroll
            for (int sq = 1; sq < 4; ++sq) {
                float2 a16 = agg16[((size_t)((b*NC + gc0 + ch)*4 + (sq-1)))*Pp + p];
                double nr = fma(l16.x, scr, (double)a16.x); nr = fma(-l16.y, sci, nr);
                double ni = fma(l16.x, sci, (double)a16.y); ni = fma( l16.y, scr, ni);
                scr = nr; sci = ni;
                carry16L[(ch*4 + sq)*256 + p] = make_float2((float)scr, (float)sci);
            }
            if (ch < 3) {
                float2 a = agg[(b*NC + gc0 + ch) * Pp + p];
                double nr = fma(l64.x, cr, (double)a.x); nr = fma(-l64.y, ci, nr);
                double ni = fma(l64.x, ci, (double)a.y); ni = fma( l64.y, cr, ni);
                cr = nr; ci = ni;
            }
        }
    }
    asm volatile("s_waitcnt vmcnt(4) lgkmcnt(0)\n\ts_barrier" ::: "memory");
    SCAN_TILE(0, 0);
    BAR_LGKM();

    floatx4 acc[4][4];
    #pragma unroll
    for (int i = 0; i < 4; ++i)
        #pragma unroll
        for (int j = 0; j < 4; ++j) acc[i][j] = (floatx4)0.f;

    #pragma unroll
    for (int kt = 0; kt < 8; ++kt) {
        const int cb = kt & 1;
        const int tb = cb * 32768;
        {
            bf16x8 af[4], bfr[4];
            #pragma unroll
            for (int fm = 0; fm < 4; ++fm)
                af[fm] = *(const bf16x8*)(aRd + tb + fm*2048 + o0);
            #pragma unroll
            for (int fn = 0; fn < 4; ++fn)
                bfr[fn] = *(const bf16x8*)(bRd + tb + fn*2048 + o0);
            __builtin_amdgcn_s_setprio(1);
            #pragma unroll
            for (int fm = 0; fm < 4; ++fm)
                #pragma unroll
                for (int fn = 0; fn < 4; ++fn)
                    acc[fm][fn] = __builtin_amdgcn_mfma_f32_16x16x32_bf16(
                        af[fm], bfr[fn], acc[fm][fn], 0, 0, 0);
            __builtin_amdgcn_s_setprio(0);
        }
        {
            bf16x8 af[4], bfr[4];
            #pragma unroll
            for (int fm = 0; fm < 4; ++fm)
                af[fm] = *(const bf16x8*)(aRd + tb + fm*2048 + o1);
            #pragma unroll
            for (int fn = 0; fn < 4; ++fn)
                bfr[fn] = *(const bf16x8*)(bRd + tb + fn*2048 + o1);
            BAR_LGKM();
            if (kt + 2 < 8) { STAGEA2(cb, kt + 2); STAGEB2(cb, kt + 2); }
            __builtin_amdgcn_sched_barrier(0);
            __builtin_amdgcn_s_setprio(1);
            #pragma unroll
            for (int fm = 0; fm < 4; ++fm)
                #pragma unroll
                for (int fn = 0; fn < 4; ++fn)
                    acc[fm][fn] = __builtin_amdgcn_mfma_f32_16x16x32_bf16(
                        af[fm], bfr[fn], acc[fm][fn], 0, 0, 0);
            __builtin_amdgcn_s_setprio(0);
        }
        if (kt < 6)       { BAR_VMN(4); SCAN_TILE(kt + 1, cb ^ 1); BAR_LGKM(); }
        else if (kt == 6) { BAR_VMN(0); SCAN_TILE(7, cb ^ 1); BAR_LGKM(); }
    }

    // epilogue: out = acc + D*u
    #pragma unroll
    for (int fm = 0; fm < 4; ++fm)
        #pragma unroll
        for (int fn = 0; fn < 4; ++fn) {
            const int col = N0 + wn*64 + fn*16 + ml;
            const float d = Dv[col];
            #pragma unroll
            for (int reg = 0; reg < 4; ++reg) {
                const long row = M0 + wm*64 + fm*16 + quad*4 + reg;
                const long o = row * 512 + col;
                out[o] = acc[fm][fn][reg] + d * __bfloat162float(ub[o]);
            }
        }
}

extern "C" void kernel_launch(void* const* d_in, const int* in_sizes, int n_in,
                              void* d_out, int out_size, void* d_ws, size_t ws_size,
                              hipStream_t stream) {
    const float* u       = (const float*)d_in[0];
    const float* Lre     = (const float*)d_in[1];
    const float* Lim     = (const float*)d_in[2];
    const float* Bmat    = (const float*)d_in[3];
    const float* Cmat    = (const float*)d_in[4];
    const float* Dv      = (const float*)d_in[5];
    const float* logstep = (const float*)d_in[6];
    float*  out = (float*)d_out;
    float2* ws  = (float2*)d_ws;

    prep<<<9217, 256, 0, stream>>>(u, Bmat, Cmat, Lre, Lim, logstep, ws);

    gemm1<<<256, 1024, 0, stream>>>(
        (const __hip_bfloat16*)(ws + UB16_OFF),
        (const __hip_bfloat16*)(ws + B1G_OFF),
        (void*)(ws + BUB_OFF),
        (const float2*)(ws + LAM_OFF),
        (float2*)(ws + AGG_OFF),
        (float2*)(ws + AGG16_OFF));

    gemm2f<<<256, 1024, 0, stream>>>(
        (const __hip_bfloat16*)(ws + BUB_OFF),
        (const __hip_bfloat16*)(ws + B3G_OFF),
        out,
        (const __hip_bfloat16*)(ws + UB16_OFF), Dv,
        (const float2*)(ws + LAM_OFF),
        (const double2*)(ws + LAMS64D_OFF),
        (const double2*)(ws + LAMS16D_OFF),
        (const float2*)(ws + AGG_OFF),
        (const float2*)(ws + AGG16_OFF));
}

// Round 8
// 207.520 us; speedup vs baseline: 1.0075x; 1.0075x over previous
//
#include <hip/hip_runtime.h>
#include <hip/hip_bf16.h>

#define Hh 512
#define Pp 256
#define Ll 4096
#define Bb 8
#define BL (Bb*Ll)      // 32768
#define Sc 64
#define NC 64

typedef __attribute__((ext_vector_type(8))) __bf16 bf16x8;
typedef __attribute__((ext_vector_type(4))) float  floatx4;

// ws offsets in float2 units (8 B each; all 16B-aligned)
#define LAM_OFF     0                        // f32 lambda_bar [256]
#define LAMS64D_OFF 512                      // double2 lambda^64 [256] (512 slots)
#define B1G_OFF     1024                     // bf16 [512 n][512 k]
#define B3G_OFF     (B1G_OFF + 65536)        // bf16 [512 n][512 k]
#define UB16_OFF    (B3G_OFF + 65536)        // bf16 u [32768][512]
#define BUB_OFF     (UB16_OFF + 4194304)     // bf16 Bu [32768][512]
#define XSB_OFF     (BUB_OFF + 4194304)      // reused: lam16 + agg16
#define AGG_OFF     (XSB_OFF + 4194304)      // float2 [512*256]

#define LAMS16D_OFF XSB_OFF                  // double2 lambda^16 [256] (512 slots)
#define AGG16_OFF   (XSB_OFF + 512)          // float2 [2048][256] sub-chunk aggs

#define OUT_ELEMS 16777216                   // then state planar [2048 re][2048 im]

#define GLL16(g, l) __builtin_amdgcn_global_load_lds( \
    (const __attribute__((address_space(1))) void*)(g), \
    (__attribute__((address_space(3))) void*)(l), 16, 0, 0)

#define BAR_LGKM()  asm volatile("s_waitcnt lgkmcnt(0)\n\ts_barrier" ::: "memory")
#define BAR_VMN(n)  asm volatile("s_waitcnt vmcnt(" #n ")\n\ts_barrier" ::: "memory")

__device__ __forceinline__ float2 cmul(float2 a, float2 b) {
    return make_float2(a.x*b.x - a.y*b.y, a.x*b.y + a.y*b.x);
}
__device__ __forceinline__ void cfma(float2& acc, float2 a, float2 b) {
    acc.x = fmaf(a.x, b.x, acc.x); acc.x = fmaf(-a.y, b.y, acc.x);
    acc.y = fmaf(a.x, b.y, acc.y); acc.y = fmaf( a.y, b.x, acc.y);
}

// ---- PREP: grid 9217 (unchanged) ----
__global__ void prep(const float* __restrict__ u,
                     const float* __restrict__ Bmat, const float* __restrict__ Cmat,
                     const float* __restrict__ Lre, const float* __restrict__ Lim,
                     const float* __restrict__ logstep, float2* __restrict__ ws) {
    int bid = blockIdx.x;
    if (bid < 8192) {
        long i = ((long)bid * 256 + threadIdx.x) * 8;
        float4 v0 = *(const float4*)(u + i);
        float4 v1 = *(const float4*)(u + i + 4);
        __align__(16) __hip_bfloat162 t[4];
        t[0] = __float22bfloat162_rn(make_float2(v0.x, v0.y));
        t[1] = __float22bfloat162_rn(make_float2(v0.z, v0.w));
        t[2] = __float22bfloat162_rn(make_float2(v1.x, v1.y));
        t[3] = __float22bfloat162_rn(make_float2(v1.z, v1.w));
        *(bf16x8*)((__hip_bfloat16*)(ws + UB16_OFF) + i) = *(const bf16x8*)t;
    } else if (bid < 8704) {
        int idx = (bid - 8192) * 256 + threadIdx.x;  // = p*512+h
        int p = idx >> 9, h = idx & 511;
        double lr = (double)Lre[p], li = (double)Lim[p];
        double st = exp((double)logstep[p]);
        double a  = lr * st, th = li * st;
        double er = exp(a);
        double lamr = er * cos(th), lami = er * sin(th);
        double nr = lamr - 1.0, ni = lami;
        double den = lr*lr + li*li;
        float gx = (float)((nr*lr + ni*li)/den), gy = (float)((ni*lr - nr*li)/den);
        float2 b = ((const float2*)Bmat)[idx];
        float re = gx*b.x - gy*b.y;
        float im = gx*b.y + gy*b.x;
        __hip_bfloat16* B1 = (__hip_bfloat16*)(ws + B1G_OFF);
        B1[(2*p)*512 + h]   = __float2bfloat16(re);
        B1[(2*p+1)*512 + h] = __float2bfloat16(im);
    } else if (bid < 9216) {
        int idx = (bid - 8704) * 256 + threadIdx.x;  // = h*256+p
        int h = idx >> 8, p = idx & 255;
        float2 c = ((const float2*)Cmat)[idx];
        __hip_bfloat162* B3 = (__hip_bfloat162*)(ws + B3G_OFF);
        B3[h*256 + p] = __float22bfloat162_rn(make_float2(2.f*c.x, -2.f*c.y));
    } else {
        int p = threadIdx.x;
        double lr = (double)Lre[p], li = (double)Lim[p];
        double st = exp((double)logstep[p]);
        double a  = lr * st, th = li * st;
        double er = exp(a);
        ws[LAM_OFF + p] = make_float2((float)(er*cos(th)), (float)(er*sin(th)));
        double er64 = exp(64.0 * a), th64 = 64.0 * th;
        ((double2*)(ws + LAMS64D_OFF))[p] = make_double2(er64*cos(th64), er64*sin(th64));
        double er16 = exp(16.0 * a), th16 = 16.0 * th;
        ((double2*)(ws + LAMS16D_OFF))[p] = make_double2(er16*cos(th16), er16*sin(th16));
    }
}

// ---- GEMM1: 16-wave 256x256, BK=64, counted-vmcnt pipeline, fused k2a epi ----
// launch_bounds(1024,4): 16 waves/block = 4 waves/EU min -> full 128-VGPR budget.
// (R7 defect: no min-waves arg -> compiler capped 64 VGPR -> acc spilled to scratch.)
#define STAGE(buf, kt) do { \
    _Pragma("unroll") \
    for (int h_ = 0; h_ < 2; ++h_) { \
        GLL16(aSrc + (h_*128)*1024 + (kt)*128, \
              ldsSt + (buf)*65536 + h_*16384); \
        GLL16(bSrc + (h_*128)*1024 + (kt)*128, \
              ldsSt + (buf)*65536 + 32768 + h_*16384); \
    } \
} while (0)

__global__ __launch_bounds__(1024, 4)
void gemm1(const __hip_bfloat16* __restrict__ A,
           const __hip_bfloat16* __restrict__ B,
           void* __restrict__ Cout,
           const float2* __restrict__ lamTab,
           float2* __restrict__ aggOut,
           float2* __restrict__ agg16Out) {
    __shared__ __align__(16) char lds[131072];
    const int tid = threadIdx.x;
    const int w = tid >> 6, l = tid & 63;

    const int idx = blockIdx.x;
    const int swz = (idx & 7) * 32 + (idx >> 3);     // T1 bijective XCD swizzle
    const int mt = swz >> 1, nt = swz & 1;
    const long M0 = (long)mt * 256;
    const int  N0 = nt * 256;

    const int rA  = l >> 3;
    const int csw = ((l & 7) ^ rA) * 16;             // T2 inverse-source swizzle
    const char* aSrc = (const char*)A + (M0 + w*8 + rA) * 1024 + csw;
    const char* bSrc = (const char*)B + (long)(N0 + w*8 + rA) * 1024 + csw;
    char* ldsSt = lds + w*1024 + l*16;

    const int quad = l >> 4, ml = l & 15, m7 = ml & 7;
    const int wm = w & 3, wn = w >> 2;
    const int o0 = ((quad    ) ^ m7) * 16;
    const int o1 = ((quad + 4) ^ m7) * 16;
    const char* aRd = lds + wm*8192 + ml*128;
    const char* bRd = lds + 32768 + wn*8192 + ml*128;

    floatx4 acc[4][4];
    #pragma unroll
    for (int i = 0; i < 4; ++i)
        #pragma unroll
        for (int j = 0; j < 4; ++j) acc[i][j] = (floatx4)0.f;

    STAGE(0, 0);
    STAGE(1, 1);
    BAR_VMN(4);

    #pragma unroll
    for (int t = 0; t < 8; ++t) {
        const int tb = (t & 1) * 65536;
        {
            bf16x8 af[4], bfr[4];
            #pragma unroll
            for (int fm = 0; fm < 4; ++fm)
                af[fm] = *(const bf16x8*)(aRd + tb + fm*2048 + o0);
            #pragma unroll
            for (int fn = 0; fn < 4; ++fn)
                bfr[fn] = *(const bf16x8*)(bRd + tb + fn*2048 + o0);
            __builtin_amdgcn_s_setprio(1);
            #pragma unroll
            for (int fm = 0; fm < 4; ++fm)
                #pragma unroll
                for (int fn = 0; fn < 4; ++fn)
                    acc[fm][fn] = __builtin_amdgcn_mfma_f32_16x16x32_bf16(
                        af[fm], bfr[fn], acc[fm][fn], 0, 0, 0);
            __builtin_amdgcn_s_setprio(0);
        }
        {
            bf16x8 af[4], bfr[4];
            #pragma unroll
            for (int fm = 0; fm < 4; ++fm)
                af[fm] = *(const bf16x8*)(aRd + tb + fm*2048 + o1);
            #pragma unroll
            for (int fn = 0; fn < 4; ++fn)
                bfr[fn] = *(const bf16x8*)(bRd + tb + fn*2048 + o1);
            BAR_LGKM();
            if (t + 2 < 8) STAGE(t & 1, t + 2);
            __builtin_amdgcn_sched_barrier(0);
            __builtin_amdgcn_s_setprio(1);
            #pragma unroll
            for (int fm = 0; fm < 4; ++fm)
                #pragma unroll
                for (int fn = 0; fn < 4; ++fn)
                    acc[fm][fn] = __builtin_amdgcn_mfma_f32_16x16x32_bf16(
                        af[fm], bfr[fn], acc[fm][fn], 0, 0, 0);
            __builtin_amdgcn_s_setprio(0);
        }
        if (t < 6)       BAR_VMN(4);
        else if (t == 6) BAR_VMN(0);
    }

    // fused store + chunk-aggregate + sub-chunk A16. Wave wm owns chunk gc0+wm;
    // j = 16*fm + 4*quad + reg, weight lam^{63-j} = p16(fm)*P4q(quad)*lam^{3-reg}.
    const int b   = (int)(M0 >> 12);
    const int gc0 = (int)((M0 >> 6) & 63);
    const int gch = gc0 + wm;
    #pragma unroll
    for (int fn = 0; fn < 4; ++fn) {
        const int col = N0 + wn*64 + fn*16 + ml;
        const int p = col >> 1;
        const float2 lam = lamTab[p];
        const float2 one = make_float2(1.f, 0.f);
        const float2 l2  = cmul(lam, lam);
        const float2 l3  = cmul(l2, lam);
        const float2 l4  = cmul(l2, l2);
        const float2 l8  = cmul(l4, l4);
        const float2 l12 = cmul(l8, l4);
        const float2 l16 = cmul(l8, l8);
        const float2 l32 = cmul(l16, l16);
        const float2 l48 = cmul(l32, l16);
        const float2 P4q = (quad==3) ? one : (quad==2) ? l4 : (quad==1) ? l8 : l12;
        float2 sc = make_float2(0.f, 0.f);
        #pragma unroll
        for (int fm = 0; fm < 4; ++fm) {
            float vr[4];
            #pragma unroll
            for (int reg = 0; reg < 4; ++reg) {
                const long row = M0 + wm*64 + fm*16 + quad*4 + reg;
                __hip_bfloat16 hv = __float2bfloat16(acc[fm][fn][reg]);
                ((__hip_bfloat16*)Cout)[row * 512 + col] = hv;
                vr[reg] = __bfloat162float(hv);
            }
            float2 s;
            s.x = fmaf(l3.x, vr[0], fmaf(l2.x, vr[1], fmaf(lam.x, vr[2], vr[3])));
            s.y = fmaf(l3.y, vr[0], fmaf(l2.y, vr[1], lam.y * vr[2]));
            const float2 p16 = (fm==3) ? one : (fm==2) ? l16 : (fm==1) ? l32 : l48;
            cfma(sc, cmul(p16, P4q), s);
            float2 tq = cmul(P4q, s);
            tq.x += __shfl_xor(tq.x, 16); tq.y += __shfl_xor(tq.y, 16);
            tq.x += __shfl_xor(tq.x, 32); tq.y += __shfl_xor(tq.y, 32);
            const float tox = __shfl_xor(tq.x, 1);
            const float toy = __shfl_xor(tq.y, 1);
            if (quad == 0 && (ml & 1) == 0)
                agg16Out[((size_t)((b*NC + gch)*4 + fm))*Pp + p] =
                    make_float2(tq.x - toy, tq.y + tox);
        }
        sc.x += __shfl_xor(sc.x, 16); sc.y += __shfl_xor(sc.y, 16);
        sc.x += __shfl_xor(sc.x, 32); sc.y += __shfl_xor(sc.y, 32);
        const float ox = __shfl_xor(sc.x, 1);
        const float oy = __shfl_xor(sc.y, 1);
        if (quad == 0 && (ml & 1) == 0) {
            aggOut[(b*NC + gch) * Pp + p] = make_float2(sc.x - oy, sc.y + ox);
        }
    }
}

// ---- GEMM2F: 16-wave, LDS-staged Bu, in-place 512-thread scan ----
// LDS: A dbuf [0,64K) | B dbuf [64K,128K) | carry16 [128K,160K).
#define STAGEA2(buf, kt) do { \
    _Pragma("unroll") \
    for (int h_ = 0; h_ < 2; ++h_) { \
        GLL16(aSrc + (h_*128)*1024 + (kt)*128, \
              ldsA + (buf)*32768 + h_*16384); \
    } \
} while (0)
#define STAGEB2(buf, kt) do { \
    _Pragma("unroll") \
    for (int h_ = 0; h_ < 2; ++h_) { \
        GLL16(bSrc + (h_*128)*1024 + (kt)*128, \
              ldsB + (buf)*32768 + h_*16384); \
    } \
} while (0)

// in-place scan of one K-tile (32 complex p, 256 rows) by threads 0..511
#define SCAN_TILE(ktC, bufA) do { \
    if (tid < 512) { \
        const int s16_ = tid >> 5; \
        const float2 lam_ = lamK[ktC]; \
        float2 x_ = carry16L[s16_*256 + (ktC)*32 + p5g]; \
        char* base_ = lds + (bufA)*32768; \
        _Pragma("unroll") \
        for (int jj_ = 0; jj_ < 16; ++jj_) { \
            const int j_ = (s16_ << 4) + jj_; \
            char* cell_ = base_ + j_*128 + ((((p5g >> 2) ^ (j_ & 7)) << 4) | ((p5g & 3) << 2)); \
            float2 v_ = __bfloat1622float2(*(const __hip_bfloat162*)cell_); \
            float nr_ = fmaf(lam_.x, x_.x, v_.x); nr_ = fmaf(-lam_.y, x_.y, nr_); \
            float ni_ = fmaf(lam_.x, x_.y, v_.y); ni_ = fmaf( lam_.y, x_.x, ni_); \
            x_.x = nr_; x_.y = ni_; \
            *(__hip_bfloat162*)cell_ = __float22bfloat162_rn(x_); \
        } \
        if (s16_ == 15 && gc0 == 60 && nt == 0) { \
            out[OUT_ELEMS + b * Pp + (ktC)*32 + p5g] = x_.x; \
            out[OUT_ELEMS + Bb * Pp + b * Pp + (ktC)*32 + p5g] = x_.y; \
        } \
    } \
} while (0)

__global__ __launch_bounds__(1024, 4)
void gemm2f(const __hip_bfloat16* __restrict__ A,   // Bu bf16 [32768][512]
            const __hip_bfloat16* __restrict__ Bg,  // B3G [512 n][512 k]
            float* __restrict__ out,
            const __hip_bfloat16* __restrict__ ub,
            const float* __restrict__ Dv,
            const float2* __restrict__ lamTab,
            const double2* __restrict__ lam64,
            const double2* __restrict__ lam16,
            const float2* __restrict__ agg,
            const float2* __restrict__ agg16) {
    __shared__ __align__(16) char lds[163840];
    const int tid = threadIdx.x;
    const int w = tid >> 6, l = tid & 63;
    const int idx = blockIdx.x;
    const int swz = (idx & 7) * 32 + (idx >> 3);
    const int mt = swz >> 1, nt = swz & 1;
    const long M0 = (long)mt * 256;
    const int  N0 = nt * 256;
    const int b   = (int)(M0 >> 12);
    const int gc0 = (int)((M0 >> 6) & 63);   // multiple of 4

    const int rA  = l >> 3;
    const int csw = ((l & 7) ^ rA) * 16;
    const char* aSrc = (const char*)A + (M0 + w*8 + rA) * 1024 + csw;
    const char* bSrc = (const char*)Bg + (long)(N0 + w*8 + rA) * 1024 + csw;
    char* ldsA = lds + w*1024 + l*16;
    char* ldsB = lds + 65536 + w*1024 + l*16;

    const int quad = l >> 4, ml = l & 15, m7 = ml & 7;
    const int wm = w & 3, wn = w >> 2;
    const int o0 = ((quad    ) ^ m7) * 16;
    const int o1 = ((quad + 4) ^ m7) * 16;
    const char* aRd = lds + wm*8192 + ml*128;
    const char* bRd = lds + 65536 + wn*8192 + ml*128;
    float2* carry16L = (float2*)(lds + 131072);   // [16][256]

    const int p5g = tid & 31;
    float2 lamK[8];
    #pragma unroll
    for (int kt = 0; kt < 8; ++kt) lamK[kt] = lamTab[kt*32 + p5g];

    STAGEA2(0, 0); STAGEB2(0, 0);
    STAGEA2(1, 1); STAGEB2(1, 1);

    // chunk carries (exact fp64 chain) + fp64 sub-chunk carries -> LDS
    if (tid < 256) {
        const int p = tid;
        const double2 l64 = lam64[p];
        const double2 l16 = lam16[p];
        double cr = 0.0, ci = 0.0;
        for (int cp = 0; cp + 4 <= gc0; cp += 4) {
            float2 a0 = agg[(b*NC + cp    ) * Pp + p];
            float2 a1 = agg[(b*NC + cp + 1) * Pp + p];
            float2 a2 = agg[(b*NC + cp + 2) * Pp + p];
            float2 a3 = agg[(b*NC + cp + 3) * Pp + p];
            double nr, ni;
            nr = fma(l64.x, cr, (double)a0.x); nr = fma(-l64.y, ci, nr);
            ni = fma(l64.x, ci, (double)a0.y); ni = fma( l64.y, cr, ni); cr = nr; ci = ni;
            nr = fma(l64.x, cr, (double)a1.x); nr = fma(-l64.y, ci, nr);
            ni = fma(l64.x, ci, (double)a1.y); ni = fma( l64.y, cr, ni); cr = nr; ci = ni;
            nr = fma(l64.x, cr, (double)a2.x); nr = fma(-l64.y, ci, nr);
            ni = fma(l64.x, ci, (double)a2.y); ni = fma( l64.y, cr, ni); cr = nr; ci = ni;
            nr = fma(l64.x, cr, (double)a3.x); nr = fma(-l64.y, ci, nr);
            ni = fma(l64.x, ci, (double)a3.y); ni = fma( l64.y, cr, ni); cr = nr; ci = ni;
        }
        #pragma unroll
        for (int ch = 0; ch < 4; ++ch) {
            carry16L[(ch*4 + 0)*256 + p] = make_float2((float)cr, (float)ci);
            double scr = cr, sci = ci;
            #pragma unroll
            for (int sq = 1; sq < 4; ++sq) {
                float2 a16 = agg16[((size_t)((b*NC + gc0 + ch)*4 + (sq-1)))*Pp + p];
                double nr = fma(l16.x, scr, (double)a16.x); nr = fma(-l16.y, sci, nr);
                double ni = fma(l16.x, sci, (double)a16.y); ni = fma( l16.y, scr, ni);
                scr = nr; sci = ni;
                carry16L[(ch*4 + sq)*256 + p] = make_float2((float)scr, (float)sci);
            }
            if (ch < 3) {
                float2 a = agg[(b*NC + gc0 + ch) * Pp + p];
                double nr = fma(l64.x, cr, (double)a.x); nr = fma(-l64.y, ci, nr);
                double ni = fma(l64.x, ci, (double)a.y); ni = fma( l64.y, cr, ni);
                cr = nr; ci = ni;
            }
        }
    }
    asm volatile("s_waitcnt vmcnt(4) lgkmcnt(0)\n\ts_barrier" ::: "memory");
    SCAN_TILE(0, 0);
    BAR_LGKM();

    floatx4 acc[4][4];
    #pragma unroll
    for (int i = 0; i < 4; ++i)
        #pragma unroll
        for (int j = 0; j < 4; ++j) acc[i][j] = (floatx4)0.f;

    #pragma unroll
    for (int kt = 0; kt < 8; ++kt) {
        const int cb = kt & 1;
        const int tb = cb * 32768;
        {
            bf16x8 af[4], bfr[4];
            #pragma unroll
            for (int fm = 0; fm < 4; ++fm)
                af[fm] = *(const bf16x8*)(aRd + tb + fm*2048 + o0);
            #pragma unroll
            for (int fn = 0; fn < 4; ++fn)
                bfr[fn] = *(const bf16x8*)(bRd + tb + fn*2048 + o0);
            __builtin_amdgcn_s_setprio(1);
            #pragma unroll
            for (int fm = 0; fm < 4; ++fm)
                #pragma unroll
                for (int fn = 0; fn < 4; ++fn)
                    acc[fm][fn] = __builtin_amdgcn_mfma_f32_16x16x32_bf16(
                        af[fm], bfr[fn], acc[fm][fn], 0, 0, 0);
            __builtin_amdgcn_s_setprio(0);
        }
        {
            bf16x8 af[4], bfr[4];
            #pragma unroll
            for (int fm = 0; fm < 4; ++fm)
                af[fm] = *(const bf16x8*)(aRd + tb + fm*2048 + o1);
            #pragma unroll
            for (int fn = 0; fn < 4; ++fn)
                bfr[fn] = *(const bf16x8*)(bRd + tb + fn*2048 + o1);
            BAR_LGKM();
            if (kt + 2 < 8) { STAGEA2(cb, kt + 2); STAGEB2(cb, kt + 2); }
            __builtin_amdgcn_sched_barrier(0);
            __builtin_amdgcn_s_setprio(1);
            #pragma unroll
            for (int fm = 0; fm < 4; ++fm)
                #pragma unroll
                for (int fn = 0; fn < 4; ++fn)
                    acc[fm][fn] = __builtin_amdgcn_mfma_f32_16x16x32_bf16(
                        af[fm], bfr[fn], acc[fm][fn], 0, 0, 0);
            __builtin_amdgcn_s_setprio(0);
        }
        if (kt < 6)       { BAR_VMN(4); SCAN_TILE(kt + 1, cb ^ 1); BAR_LGKM(); }
        else if (kt == 6) { BAR_VMN(0); SCAN_TILE(7, cb ^ 1); BAR_LGKM(); }
    }

    // epilogue: out = acc + D*u
    #pragma unroll
    for (int fm = 0; fm < 4; ++fm)
        #pragma unroll
        for (int fn = 0; fn < 4; ++fn) {
            const int col = N0 + wn*64 + fn*16 + ml;
            const float d = Dv[col];
            #pragma unroll
            for (int reg = 0; reg < 4; ++reg) {
                const long row = M0 + wm*64 + fm*16 + quad*4 + reg;
                const long o = row * 512 + col;
                out[o] = acc[fm][fn][reg] + d * __bfloat162float(ub[o]);
            }
        }
}

extern "C" void kernel_launch(void* const* d_in, const int* in_sizes, int n_in,
                              void* d_out, int out_size, void* d_ws, size_t ws_size,
                              hipStream_t stream) {
    const float* u       = (const float*)d_in[0];
    const float* Lre     = (const float*)d_in[1];
    const float* Lim     = (const float*)d_in[2];
    const float* Bmat    = (const float*)d_in[3];
    const float* Cmat    = (const float*)d_in[4];
    const float* Dv      = (const float*)d_in[5];
    const float* logstep = (const float*)d_in[6];
    float*  out = (float*)d_out;
    float2* ws  = (float2*)d_ws;

    prep<<<9217, 256, 0, stream>>>(u, Bmat, Cmat, Lre, Lim, logstep, ws);

    gemm1<<<256, 1024, 0, stream>>>(
        (const __hip_bfloat16*)(ws + UB16_OFF),
        (const __hip_bfloat16*)(ws + B1G_OFF),
        (void*)(ws + BUB_OFF),
        (const float2*)(ws + LAM_OFF),
        (float2*)(ws + AGG_OFF),
        (float2*)(ws + AGG16_OFF));

    gemm2f<<<256, 1024, 0, stream>>>(
        (const __hip_bfloat16*)(ws + BUB_OFF),
        (const __hip_bfloat16*)(ws + B3G_OFF),
        out,
        (const __hip_bfloat16*)(ws + UB16_OFF), Dv,
        (const float2*)(ws + LAM_OFF),
        (const double2*)(ws + LAMS64D_OFF),
        (const double2*)(ws + LAMS16D_OFF),
        (const float2*)(ws + AGG_OFF),
        (const float2*)(ws + AGG16_OFF));
}

// Round 9
// 183.245 us; speedup vs baseline: 1.1410x; 1.1325x over previous
//
#include <hip/hip_runtime.h>
#include <hip/hip_bf16.h>

#define Hh 512
#define Pp 256
#define Ll 4096
#define Bb 8
#define BL (Bb*Ll)      // 32768
#define Sc 64
#define NC 64

typedef __attribute__((ext_vector_type(8))) __bf16 bf16x8;
typedef __attribute__((ext_vector_type(4))) float  floatx4;

// ws offsets in float2 units (8 B each; all 16B-aligned)
#define LAM_OFF     0                        // f32 lambda_bar [256]
#define LAMS64D_OFF 512                      // double2 lambda^64 [256] (512 slots)
#define B1G_OFF     1024                     // bf16 [512 n][512 k]
#define B3G_OFF     (B1G_OFF + 65536)        // bf16 [512 n][512 k]
#define UB16_OFF    (B3G_OFF + 65536)        // bf16 u [32768][512]
#define BUB_OFF     (UB16_OFF + 4194304)     // bf16 Bu [32768][512]
#define XSB_OFF     (BUB_OFF + 4194304)      // reused: lam16 + agg16
#define AGG_OFF     (XSB_OFF + 4194304)      // float2 [512*256]

#define LAMS16D_OFF XSB_OFF                  // double2 lambda^16 [256] (512 slots)
#define AGG16_OFF   (XSB_OFF + 512)          // float2 [2048][256] sub-chunk aggs

#define OUT_ELEMS 16777216                   // then state planar [2048 re][2048 im]

#define GLL16(g, l) __builtin_amdgcn_global_load_lds( \
    (const __attribute__((address_space(1))) void*)(g), \
    (__attribute__((address_space(3))) void*)(l), 16, 0, 0)

#define BAR_LGKM()  asm volatile("s_waitcnt lgkmcnt(0)\n\ts_barrier" ::: "memory")
#define BAR_VMN(n)  asm volatile("s_waitcnt vmcnt(" #n ")\n\ts_barrier" ::: "memory")

__device__ __forceinline__ float2 cmul(float2 a, float2 b) {
    return make_float2(a.x*b.x - a.y*b.y, a.x*b.y + a.y*b.x);
}
__device__ __forceinline__ void cfma(float2& acc, float2 a, float2 b) {
    acc.x = fmaf(a.x, b.x, acc.x); acc.x = fmaf(-a.y, b.y, acc.x);
    acc.y = fmaf(a.x, b.y, acc.y); acc.y = fmaf( a.y, b.x, acc.y);
}

// ---- PREP: grid 9217 (unchanged) ----
__global__ void prep(const float* __restrict__ u,
                     const float* __restrict__ Bmat, const float* __restrict__ Cmat,
                     const float* __restrict__ Lre, const float* __restrict__ Lim,
                     const float* __restrict__ logstep, float2* __restrict__ ws) {
    int bid = blockIdx.x;
    if (bid < 8192) {
        long i = ((long)bid * 256 + threadIdx.x) * 8;
        float4 v0 = *(const float4*)(u + i);
        float4 v1 = *(const float4*)(u + i + 4);
        __align__(16) __hip_bfloat162 t[4];
        t[0] = __float22bfloat162_rn(make_float2(v0.x, v0.y));
        t[1] = __float22bfloat162_rn(make_float2(v0.z, v0.w));
        t[2] = __float22bfloat162_rn(make_float2(v1.x, v1.y));
        t[3] = __float22bfloat162_rn(make_float2(v1.z, v1.w));
        *(bf16x8*)((__hip_bfloat16*)(ws + UB16_OFF) + i) = *(const bf16x8*)t;
    } else if (bid < 8704) {
        int idx = (bid - 8192) * 256 + threadIdx.x;  // = p*512+h
        int p = idx >> 9, h = idx & 511;
        double lr = (double)Lre[p], li = (double)Lim[p];
        double st = exp((double)logstep[p]);
        double a  = lr * st, th = li * st;
        double er = exp(a);
        double lamr = er * cos(th), lami = er * sin(th);
        double nr = lamr - 1.0, ni = lami;
        double den = lr*lr + li*li;
        float gx = (float)((nr*lr + ni*li)/den), gy = (float)((ni*lr - nr*li)/den);
        float2 b = ((const float2*)Bmat)[idx];
        float re = gx*b.x - gy*b.y;
        float im = gx*b.y + gy*b.x;
        __hip_bfloat16* B1 = (__hip_bfloat16*)(ws + B1G_OFF);
        B1[(2*p)*512 + h]   = __float2bfloat16(re);
        B1[(2*p+1)*512 + h] = __float2bfloat16(im);
    } else if (bid < 9216) {
        int idx = (bid - 8704) * 256 + threadIdx.x;  // = h*256+p
        int h = idx >> 8, p = idx & 255;
        float2 c = ((const float2*)Cmat)[idx];
        __hip_bfloat162* B3 = (__hip_bfloat162*)(ws + B3G_OFF);
        B3[h*256 + p] = __float22bfloat162_rn(make_float2(2.f*c.x, -2.f*c.y));
    } else {
        int p = threadIdx.x;
        double lr = (double)Lre[p], li = (double)Lim[p];
        double st = exp((double)logstep[p]);
        double a  = lr * st, th = li * st;
        double er = exp(a);
        ws[LAM_OFF + p] = make_float2((float)(er*cos(th)), (float)(er*sin(th)));
        double er64 = exp(64.0 * a), th64 = 64.0 * th;
        ((double2*)(ws + LAMS64D_OFF))[p] = make_double2(er64*cos(th64), er64*sin(th64));
        double er16 = exp(16.0 * a), th16 = 16.0 * th;
        ((double2*)(ws + LAMS16D_OFF))[p] = make_double2(er16*cos(th16), er16*sin(th16));
    }
}

// ---- GEMM1: R6-proven 8-wave 256x256 BK=64 + LDS-coalesced C-store ----
#define STAGE(buf, kt) do { \
    _Pragma("unroll") \
    for (int h_ = 0; h_ < 2; ++h_) { \
        _Pragma("unroll") \
        for (int r_ = 0; r_ < 2; ++r_) { \
            GLL16(aSrc + (h_*128 + r_*64)*1024 + (kt)*128, \
                  ldsSt + (buf)*65536 + h_*16384 + r_*8192); \
            GLL16(bSrc + (h_*128 + r_*64)*1024 + (kt)*128, \
                  ldsSt + (buf)*65536 + 32768 + h_*16384 + r_*8192); \
        } \
    } \
} while (0)

__global__ __launch_bounds__(512, 2)
void gemm1(const __hip_bfloat16* __restrict__ A,
           const __hip_bfloat16* __restrict__ B,
           void* __restrict__ Cout,
           const float2* __restrict__ lamTab,
           float2* __restrict__ aggOut,
           float2* __restrict__ agg16Out) {
    __shared__ __align__(16) char lds[131072];
    const int tid = threadIdx.x;
    const int w = tid >> 6, l = tid & 63;

    const int idx = blockIdx.x;
    const int swz = (idx & 7) * 32 + (idx >> 3);     // T1 bijective XCD swizzle
    const int mt = swz >> 1, nt = swz & 1;
    const long M0 = (long)mt * 256;
    const int  N0 = nt * 256;

    const int rA  = l >> 3;
    const int csw = ((l & 7) ^ rA) * 16;             // T2 inverse-source swizzle
    const char* aSrc = (const char*)A + (M0 + w*8 + rA) * 1024 + csw;
    const char* bSrc = (const char*)B + (long)(N0 + w*8 + rA) * 1024 + csw;
    char* ldsSt = lds + w*1024 + l*16;

    const int quad = l >> 4, ml = l & 15, m7 = ml & 7;
    const int wm = w & 1, wn = w >> 1;
    const int o0 = ((quad    ) ^ m7) * 16;
    const int o1 = ((quad + 4) ^ m7) * 16;
    const char* aRd = lds + wm*16384 + ml*128;
    const char* bRd = lds + 32768 + wn*8192 + ml*128;

    floatx4 acc[8][4];
    #pragma unroll
    for (int i = 0; i < 8; ++i)
        #pragma unroll
        for (int j = 0; j < 4; ++j) acc[i][j] = (floatx4)0.f;

    STAGE(0, 0);
    STAGE(1, 1);
    BAR_VMN(8);

    #pragma unroll
    for (int t = 0; t < 8; ++t) {
        const int tb = (t & 1) * 65536;
        {
            bf16x8 af[8], bfr[4];
            #pragma unroll
            for (int fm = 0; fm < 8; ++fm)
                af[fm] = *(const bf16x8*)(aRd + tb + fm*2048 + o0);
            #pragma unroll
            for (int fn = 0; fn < 4; ++fn)
                bfr[fn] = *(const bf16x8*)(bRd + tb + fn*2048 + o0);
            __builtin_amdgcn_s_setprio(1);
            #pragma unroll
            for (int fm = 0; fm < 8; ++fm)
                #pragma unroll
                for (int fn = 0; fn < 4; ++fn)
                    acc[fm][fn] = __builtin_amdgcn_mfma_f32_16x16x32_bf16(
                        af[fm], bfr[fn], acc[fm][fn], 0, 0, 0);
            __builtin_amdgcn_s_setprio(0);
        }
        {
            bf16x8 af[8], bfr[4];
            #pragma unroll
            for (int fm = 0; fm < 8; ++fm)
                af[fm] = *(const bf16x8*)(aRd + tb + fm*2048 + o1);
            #pragma unroll
            for (int fn = 0; fn < 4; ++fn)
                bfr[fn] = *(const bf16x8*)(bRd + tb + fn*2048 + o1);
            BAR_LGKM();
            if (t + 2 < 8) STAGE(t & 1, t + 2);
            __builtin_amdgcn_sched_barrier(0);
            __builtin_amdgcn_s_setprio(1);
            #pragma unroll
            for (int fm = 0; fm < 8; ++fm)
                #pragma unroll
                for (int fn = 0; fn < 4; ++fn)
                    acc[fm][fn] = __builtin_amdgcn_mfma_f32_16x16x32_bf16(
                        af[fm], bfr[fn], acc[fm][fn], 0, 0, 0);
            __builtin_amdgcn_s_setprio(0);
        }
        if (t < 6)       BAR_VMN(8);
        else if (t == 6) BAR_VMN(0);
    }

    // epilogue: aggregates (numerics identical to R6) + C-tile via LDS for
    // coalesced 16B-lane stores (R6's direct bf16 stores -> 32B partial-line
    // segments -> WRITE_SIZE inflation 59.3 vs 38 MB ideal).
    __syncthreads();   // all waves done reading LDS K-buffers
    __hip_bfloat16* ldsC = (__hip_bfloat16*)lds;   // [256 rows][256 cols]
    const int b   = (int)(M0 >> 12);
    const int gc0 = (int)((M0 >> 6) & 63);
    #pragma unroll
    for (int fn = 0; fn < 4; ++fn) {
        const int col = N0 + wn*64 + fn*16 + ml;
        const int cl  = wn*64 + fn*16 + ml;          // local col
        const int p = col >> 1;
        const float2 lam = lamTab[p];
        const float2 one = make_float2(1.f, 0.f);
        const float2 l2  = cmul(lam, lam);
        const float2 l3  = cmul(l2, lam);
        const float2 l4  = cmul(l2, l2);
        const float2 l8  = cmul(l4, l4);
        const float2 l12 = cmul(l8, l4);
        const float2 l16 = cmul(l8, l8);
        const float2 l32 = cmul(l16, l16);
        const float2 l48 = cmul(l32, l16);
        const float2 P4q = (quad==3) ? one : (quad==2) ? l4 : (quad==1) ? l8 : l12;
        #pragma unroll
        for (int c = 0; c < 2; ++c) {
            float2 sc = make_float2(0.f, 0.f);
            #pragma unroll
            for (int a = 0; a < 4; ++a) {
                const int fm = c*4 + a;
                float vr[4];
                #pragma unroll
                for (int reg = 0; reg < 4; ++reg) {
                    const int rl = wm*128 + fm*16 + quad*4 + reg;   // local row
                    __hip_bfloat16 hv = __float2bfloat16(acc[fm][fn][reg]);
                    ldsC[rl*256 + cl] = hv;
                    vr[reg] = __bfloat162float(hv);
                }
                float2 s;
                s.x = fmaf(l3.x, vr[0], fmaf(l2.x, vr[1], fmaf(lam.x, vr[2], vr[3])));
                s.y = fmaf(l3.y, vr[0], fmaf(l2.y, vr[1], lam.y * vr[2]));
                const float2 p16 = (a==3) ? one : (a==2) ? l16 : (a==1) ? l32 : l48;
                cfma(sc, cmul(p16, P4q), s);
                float2 tq = cmul(P4q, s);
                tq.x += __shfl_xor(tq.x, 16); tq.y += __shfl_xor(tq.y, 16);
                tq.x += __shfl_xor(tq.x, 32); tq.y += __shfl_xor(tq.y, 32);
                const float tox = __shfl_xor(tq.x, 1);
                const float toy = __shfl_xor(tq.y, 1);
                if (quad == 0 && (ml & 1) == 0)
                    agg16Out[((size_t)((b*NC + gc0 + wm*2 + c)*4 + a))*Pp + p] =
                        make_float2(tq.x - toy, tq.y + tox);
            }
            sc.x += __shfl_xor(sc.x, 16); sc.y += __shfl_xor(sc.y, 16);
            sc.x += __shfl_xor(sc.x, 32); sc.y += __shfl_xor(sc.y, 32);
            const float ox = __shfl_xor(sc.x, 1);
            const float oy = __shfl_xor(sc.y, 1);
            if (quad == 0 && (ml & 1) == 0) {
                aggOut[(b*NC + gc0 + wm*2 + c) * Pp + p] =
                    make_float2(sc.x - oy, sc.y + ox);
            }
        }
    }
    __syncthreads();
    {   // coalesced store: 16 passes x (16 rows x 512B), 16B per lane
        const int rr = tid >> 5;             // 0..15
        const int cb = (tid & 31) * 16;      // byte col within 512B row
        #pragma unroll
        for (int pass = 0; pass < 16; ++pass) {
            const int r = pass * 16 + rr;
            *(float4*)((char*)Cout + (M0 + r) * 1024 + (long)N0 * 2 + cb) =
                *(const float4*)(lds + r * 512 + cb);
        }
    }
}

// ---- GEMM2F: R6-proven structure + batched-read scan (breaks serial LDS chain) ----
// LDS: A dbuf [0,64K) | B dbuf [64K,128K) | carry16 [128K,160K).
#define STAGEA2(buf, kt) do { \
    _Pragma("unroll") \
    for (int h_ = 0; h_ < 2; ++h_) { \
        _Pragma("unroll") \
        for (int r_ = 0; r_ < 2; ++r_) { \
            GLL16(aSrc + (h_*128 + r_*64)*1024 + (kt)*128, \
                  ldsA + (buf)*32768 + h_*16384 + r_*8192); \
        } \
    } \
} while (0)
#define STAGEB2(buf, kt) do { \
    _Pragma("unroll") \
    for (int h_ = 0; h_ < 2; ++h_) { \
        _Pragma("unroll") \
        for (int r_ = 0; r_ < 2; ++r_) { \
            GLL16(bSrc + (h_*128 + r_*64)*1024 + (kt)*128, \
                  ldsB + (buf)*32768 + h_*16384 + r_*8192); \
        } \
    } \
} while (0)

// scan of one K-tile: batch-issue all 16 independent LDS reads (one latency),
// then the serial 16-step register recurrence with fire-and-forget writes.
#define SCAN_TILE(ktC, bufA) do { \
    const int s16_ = tid >> 5; \
    const float2 lam_ = lamK[ktC]; \
    float2 x_ = carry16L[s16_*256 + (ktC)*32 + p5g]; \
    char* base_ = lds + (bufA)*32768; \
    float2 v_[16]; \
    _Pragma("unroll") \
    for (int jj_ = 0; jj_ < 16; ++jj_) { \
        const int j_ = (s16_ << 4) + jj_; \
        v_[jj_] = __bfloat1622float2(*(const __hip_bfloat162*)(base_ + j_*128 + \
            ((((p5g >> 2) ^ (j_ & 7)) << 4) | ((p5g & 3) << 2)))); \
    } \
    _Pragma("unroll") \
    for (int jj_ = 0; jj_ < 16; ++jj_) { \
        const int j_ = (s16_ << 4) + jj_; \
        float nr_ = fmaf(lam_.x, x_.x, v_[jj_].x); nr_ = fmaf(-lam_.y, x_.y, nr_); \
        float ni_ = fmaf(lam_.x, x_.y, v_[jj_].y); ni_ = fmaf( lam_.y, x_.x, ni_); \
        x_.x = nr_; x_.y = ni_; \
        *(__hip_bfloat162*)(base_ + j_*128 + \
            ((((p5g >> 2) ^ (j_ & 7)) << 4) | ((p5g & 3) << 2))) = \
            __float22bfloat162_rn(x_); \
    } \
    if (s16_ == 15 && gc0 == 60 && nt == 0) { \
        out[OUT_ELEMS + b * Pp + (ktC)*32 + p5g] = x_.x; \
        out[OUT_ELEMS + Bb * Pp + b * Pp + (ktC)*32 + p5g] = x_.y; \
    } \
} while (0)

__global__ __launch_bounds__(512, 2)
void gemm2f(const __hip_bfloat16* __restrict__ A,   // Bu bf16 [32768][512]
            const __hip_bfloat16* __restrict__ Bg,  // B3G [512 n][512 k]
            float* __restrict__ out,
            const __hip_bfloat16* __restrict__ ub,
            const float* __restrict__ Dv,
            const float2* __restrict__ lamTab,
            const double2* __restrict__ lam64,
            const double2* __restrict__ lam16,
            const float2* __restrict__ agg,
            const float2* __restrict__ agg16) {
    __shared__ __align__(16) char lds[163840];
    const int tid = threadIdx.x;
    const int w = tid >> 6, l = tid & 63;
    const int idx = blockIdx.x;
    const int swz = (idx & 7) * 32 + (idx >> 3);
    const int mt = swz >> 1, nt = swz & 1;
    const long M0 = (long)mt * 256;
    const int  N0 = nt * 256;
    const int b   = (int)(M0 >> 12);
    const int gc0 = (int)((M0 >> 6) & 63);   // multiple of 4

    const int rA  = l >> 3;
    const int csw = ((l & 7) ^ rA) * 16;
    const char* aSrc = (const char*)A + (M0 + w*8 + rA) * 1024 + csw;
    const char* bSrc = (const char*)Bg + (long)(N0 + w*8 + rA) * 1024 + csw;
    char* ldsA = lds + w*1024 + l*16;
    char* ldsB = lds + 65536 + w*1024 + l*16;

    const int quad = l >> 4, ml = l & 15, m7 = ml & 7;
    const int wm = w & 1, wn = w >> 1;
    const int o0 = ((quad    ) ^ m7) * 16;
    const int o1 = ((quad + 4) ^ m7) * 16;
    const char* aRd = lds + wm*16384 + ml*128;
    const char* bRd = lds + 65536 + wn*8192 + ml*128;
    float2* carry16L = (float2*)(lds + 131072);   // [16][256]

    const int p5g = tid & 31;
    float2 lamK[8];
    #pragma unroll
    for (int kt = 0; kt < 8; ++kt) lamK[kt] = lamTab[kt*32 + p5g];

    STAGEA2(0, 0); STAGEB2(0, 0);
    STAGEA2(1, 1); STAGEB2(1, 1);

    // chunk carries (exact fp64 chain) + fp64 sub-chunk carries -> LDS
    if (tid < 256) {
        const int p = tid;
        const double2 l64 = lam64[p];
        const double2 l16 = lam16[p];
        double cr = 0.0, ci = 0.0;
        for (int cp = 0; cp + 4 <= gc0; cp += 4) {
            float2 a0 = agg[(b*NC + cp    ) * Pp + p];
            float2 a1 = agg[(b*NC + cp + 1) * Pp + p];
            float2 a2 = agg[(b*NC + cp + 2) * Pp + p];
            float2 a3 = agg[(b*NC + cp + 3) * Pp + p];
            double nr, ni;
            nr = fma(l64.x, cr, (double)a0.x); nr = fma(-l64.y, ci, nr);
            ni = fma(l64.x, ci, (double)a0.y); ni = fma( l64.y, cr, ni); cr = nr; ci = ni;
            nr = fma(l64.x, cr, (double)a1.x); nr = fma(-l64.y, ci, nr);
            ni = fma(l64.x, ci, (double)a1.y); ni = fma( l64.y, cr, ni); cr = nr; ci = ni;
            nr = fma(l64.x, cr, (double)a2.x); nr = fma(-l64.y, ci, nr);
            ni = fma(l64.x, ci, (double)a2.y); ni = fma( l64.y, cr, ni); cr = nr; ci = ni;
            nr = fma(l64.x, cr, (double)a3.x); nr = fma(-l64.y, ci, nr);
            ni = fma(l64.x, ci, (double)a3.y); ni = fma( l64.y, cr, ni); cr = nr; ci = ni;
        }
        #pragma unroll
        for (int ch = 0; ch < 4; ++ch) {
            carry16L[(ch*4 + 0)*256 + p] = make_float2((float)cr, (float)ci);
            double scr = cr, sci = ci;
            #pragma unroll
            for (int sq = 1; sq < 4; ++sq) {
                float2 a16 = agg16[((size_t)((b*NC + gc0 + ch)*4 + (sq-1)))*Pp + p];
                double nr = fma(l16.x, scr, (double)a16.x); nr = fma(-l16.y, sci, nr);
                double ni = fma(l16.x, sci, (double)a16.y); ni = fma( l16.y, scr, ni);
                scr = nr; sci = ni;
                carry16L[(ch*4 + sq)*256 + p] = make_float2((float)scr, (float)sci);
            }
            if (ch < 3) {
                float2 a = agg[(b*NC + gc0 + ch) * Pp + p];
                double nr = fma(l64.x, cr, (double)a.x); nr = fma(-l64.y, ci, nr);
                double ni = fma(l64.x, ci, (double)a.y); ni = fma( l64.y, cr, ni);
                cr = nr; ci = ni;
            }
        }
    }
    asm volatile("s_waitcnt vmcnt(8) lgkmcnt(0)\n\ts_barrier" ::: "memory");
    SCAN_TILE(0, 0);
    BAR_LGKM();

    floatx4 acc[8][4];
    #pragma unroll
    for (int i = 0; i < 8; ++i)
        #pragma unroll
        for (int j = 0; j < 4; ++j) acc[i][j] = (floatx4)0.f;

    #pragma unroll
    for (int kt = 0; kt < 8; ++kt) {
        const int cb = kt & 1;
        const int tb = cb * 32768;
        {
            bf16x8 af[8], bfr[4];
            #pragma unroll
            for (int fm = 0; fm < 8; ++fm)
                af[fm] = *(const bf16x8*)(aRd + tb + fm*2048 + o0);
            #pragma unroll
            for (int fn = 0; fn < 4; ++fn)
                bfr[fn] = *(const bf16x8*)(bRd + tb + fn*2048 + o0);
            __builtin_amdgcn_s_setprio(1);
            #pragma unroll
            for (int fm = 0; fm < 8; ++fm)
                #pragma unroll
                for (int fn = 0; fn < 4; ++fn)
                    acc[fm][fn] = __builtin_amdgcn_mfma_f32_16x16x32_bf16(
                        af[fm], bfr[fn], acc[fm][fn], 0, 0, 0);
            __builtin_amdgcn_s_setprio(0);
        }
        {
            bf16x8 af[8], bfr[4];
            #pragma unroll
            for (int fm = 0; fm < 8; ++fm)
                af[fm] = *(const bf16x8*)(aRd + tb + fm*2048 + o1);
            #pragma unroll
            for (int fn = 0; fn < 4; ++fn)
                bfr[fn] = *(const bf16x8*)(bRd + tb + fn*2048 + o1);
            BAR_LGKM();
            if (kt + 2 < 8) { STAGEA2(cb, kt + 2); STAGEB2(cb, kt + 2); }
            __builtin_amdgcn_sched_barrier(0);
            __builtin_amdgcn_s_setprio(1);
            #pragma unroll
            for (int fm = 0; fm < 8; ++fm)
                #pragma unroll
                for (int fn = 0; fn < 4; ++fn)
                    acc[fm][fn] = __builtin_amdgcn_mfma_f32_16x16x32_bf16(
                        af[fm], bfr[fn], acc[fm][fn], 0, 0, 0);
            __builtin_amdgcn_s_setprio(0);
        }
        if (kt < 6)       { BAR_VMN(8); SCAN_TILE(kt + 1, cb ^ 1); BAR_LGKM(); }
        else if (kt == 6) { BAR_VMN(0); SCAN_TILE(7, cb ^ 1); BAR_LGKM(); }
    }

    // epilogue: out = acc + D*u (fp32 stores are full 64B segments -> ok direct)
    #pragma unroll
    for (int fm = 0; fm < 8; ++fm)
        #pragma unroll
        for (int fn = 0; fn < 4; ++fn) {
            const int col = N0 + wn*64 + fn*16 + ml;
            const float d = Dv[col];
            #pragma unroll
            for (int reg = 0; reg < 4; ++reg) {
                const long row = M0 + wm*128 + fm*16 + quad*4 + reg;
                const long o = row * 512 + col;
                out[o] = acc[fm][fn][reg] + d * __bfloat162float(ub[o]);
            }
        }
}

extern "C" void kernel_launch(void* const* d_in, const int* in_sizes, int n_in,
                              void* d_out, int out_size, void* d_ws, size_t ws_size,
                              hipStream_t stream) {
    const float* u       = (const float*)d_in[0];
    const float* Lre     = (const float*)d_in[1];
    const float* Lim     = (const float*)d_in[2];
    const float* Bmat    = (const float*)d_in[3];
    const float* Cmat    = (const float*)d_in[4];
    const float* Dv      = (const float*)d_in[5];
    const float* logstep = (const float*)d_in[6];
    float*  out = (float*)d_out;
    float2* ws  = (float2*)d_ws;

    prep<<<9217, 256, 0, stream>>>(u, Bmat, Cmat, Lre, Lim, logstep, ws);

    gemm1<<<256, 512, 0, stream>>>(
        (const __hip_bfloat16*)(ws + UB16_OFF),
        (const __hip_bfloat16*)(ws + B1G_OFF),
        (void*)(ws + BUB_OFF),
        (const float2*)(ws + LAM_OFF),
        (float2*)(ws + AGG_OFF),
        (float2*)(ws + AGG16_OFF));

    gemm2f<<<256, 512, 0, stream>>>(
        (const __hip_bfloat16*)(ws + BUB_OFF),
        (const __hip_bfloat16*)(ws + B3G_OFF),
        out,
        (const __hip_bfloat16*)(ws + UB16_OFF), Dv,
        (const float2*)(ws + LAM_OFF),
        (const double2*)(ws + LAMS64D_OFF),
        (const double2*)(ws + LAMS16D_OFF),
        (const float2*)(ws + AGG_OFF),
        (const float2*)(ws + AGG16_OFF));
}